// Round 10
// baseline (2156.326 us; speedup 1.0000x reference)
//
#include <hip/hip_runtime.h>

#define N1 32768
#define NP1 512
#define NS1 32
#define N2 512
#define NP2 256
#define NS2 64

// ---- exact-rounding helpers: replicate reference op-by-op (NO fma/contract) ----
__device__ __forceinline__ float fadd(float a, float b){ return __fadd_rn(a,b); }
__device__ __forceinline__ float fmul(float a, float b){ return __fmul_rn(a,b); }
__device__ __forceinline__ float fsub(float a, float b){ return __fsub_rn(a,b); }

__device__ __forceinline__ float dist3(float px,float py,float pz,float cx,float cy,float cz){
    float dx = fsub(px,cx), dy = fsub(py,cy), dz = fsub(pz,cz);
    return fadd(fadd(fmul(dx,dx), fmul(dy,dy)), fmul(dz,dz));
}
__device__ __forceinline__ float sumsq3(float x,float y,float z){
    return fadd(fadd(fmul(x,x), fmul(y,y)), fmul(z,z));
}
__device__ __forceinline__ float dot3(float ax,float ay,float az,float bx,float by,float bz){
    return fadd(fadd(fmul(ax,bx), fmul(ay,by)), fmul(az,bz));
}

__device__ __forceinline__ unsigned long long shflmax64(unsigned long long k, int off){
    unsigned long long o = __shfl_xor(k, off, 64);
    return o > k ? o : k;
}

// =====================  FPS over 32768 pts, 512 picks  =====================
// v10 hybrid exchange: block-level publish (16 slots = 2 cache lines, small
// poll footprint like R6 — the 64-slot/8-line version showed 32ms outliers),
// barrier-free consumption (parity-double-buffered wbuf kills R6's 2nd
// barrier + winner-LDS hop; one __syncthreads per iteration). All waves poll
// the 2-line region with lanes 0..15, speculative centroid load on detect,
// in-register butterfly + coord shuffle.
#define FPS1_M  16
#define FPS1_TB 256

__global__ __launch_bounds__(FPS1_TB) void fps1_kernel(const float* __restrict__ xyz,
                                                       float* __restrict__ new_xyz1,
                                                       unsigned long long* __restrict__ bests)
{
    const int m = blockIdx.x;          // chunk within batch
    const int b = blockIdx.y;          // batch
    const int t = threadIdx.x;
    const int lane = t & 63;
    const int wid  = t >> 6;           // 4 waves
    const float* xb = xyz + (size_t)b * 6 * N1;

    __shared__ unsigned long long wbuf[2][4];   // parity double-buffer

    const int base = m * (N1 / FPS1_M);   // 2048-pt chunk
    float px[8], py[8], pz[8], dd[8];
#pragma unroll
    for (int j = 0; j < 8; ++j) {
        int n = base + t + j * FPS1_TB;
        px[j] = xb[n];
        py[j] = xb[N1 + n];
        pz[j] = xb[2*N1 + n];
        dd[j] = 1e10f;
    }

    float cx = xb[0], cy = xb[N1], cz = xb[2*N1];   // first pick = index 0

    for (int s = 0; s < NP1; ++s) {
        if (m == 0 && t == 0) {
            float* o = new_xyz1 + ((size_t)b*NP1 + s)*3;
            o[0] = cx; o[1] = cy; o[2] = cz;
        }
        if (s == NP1 - 1) break;

        // update min-dists, in-thread argmax (ascending n -> first-max kept)
        float bv = -1.0f; int bi = base + t;
#pragma unroll
        for (int j = 0; j < 8; ++j) {
            float d  = dist3(px[j],py[j],pz[j],cx,cy,cz);
            float nd = fminf(dd[j], d);
            dd[j] = nd;
            if (nd > bv) { bv = nd; bi = base + t + j*FPS1_TB; }
        }
        // packed key: float bits order-isomorphic (dist>=0); tie -> min index
        unsigned long long pk = ((unsigned long long)__float_as_uint(bv) << 15)
                              | (unsigned long long)(32767 - bi);
        pk = shflmax64(pk, 1);  pk = shflmax64(pk, 2);  pk = shflmax64(pk, 4);
        pk = shflmax64(pk, 8);  pk = shflmax64(pk, 16); pk = shflmax64(pk, 32);
        if (lane == 0) wbuf[s & 1][wid] = pk;
        __syncthreads();   // the only barrier per iteration

        unsigned long long* slotPar = bests + ((size_t)b*2 + (s & 1))*FPS1_M;
        if (wid == 0) {
            unsigned long long k4 = (lane < 4) ? wbuf[s & 1][lane] : 0ull;
            k4 = shflmax64(k4, 1); k4 = shflmax64(k4, 2);
            if (lane == 0)
                __hip_atomic_store(slotPar + m, (k4 << 10) | (unsigned long long)s,
                                   __ATOMIC_RELAXED, __HIP_MEMORY_SCOPE_AGENT);
        }
        // every wave polls slots 0..15 (2 cache lines); speculative coord load
        unsigned long long myv = 0; bool done = (lane >= FPS1_M);
        float ccx = 0.f, ccy = 0.f, ccz = 0.f;
        while (__ballot(done) != 0xFFFFFFFFFFFFFFFFull) {
            if (!done) {
                unsigned long long v = __hip_atomic_load(slotPar + lane,
                                         __ATOMIC_RELAXED, __HIP_MEMORY_SCOPE_AGENT);
                if ((unsigned)(v & 1023ull) == (unsigned)s) {
                    done = true; myv = v;
                    int idx = 32767 - (int)((v >> 10) & 0x7fffull);
                    ccx = xb[idx]; ccy = xb[N1 + idx]; ccz = xb[2*N1 + idx];
                }
            }
        }
        unsigned long long w = myv;
        w = shflmax64(w, 1);  w = shflmax64(w, 2);  w = shflmax64(w, 4);
        w = shflmax64(w, 8);  w = shflmax64(w, 16); w = shflmax64(w, 32);
        int wl = (int)__ffsll(__ballot(myv == w)) - 1;   // keys unique
        cx = __shfl(ccx, wl, 64);
        cy = __shfl(ccy, wl, 64);
        cz = __shfl(ccz, wl, 64);
    }
}

// =====================  FUSED: ball query 1 (x < NP1)  +  fps2 (x == NP1)  =====================
// fps2 (8 long-running blocks) overlaps ball1's 4096 short blocks instead of
// running serially after it. 64 threads/block for both paths.
__global__ __launch_bounds__(64) void ball1_fps2_kernel(const float* __restrict__ xyz,
                                                        const float* __restrict__ new_xyz1,
                                                        int* __restrict__ idx1, float r2,
                                                        float* __restrict__ new_xyz2,
                                                        float* __restrict__ out0)
{
    const int b = blockIdx.y;
    const int lane = threadIdx.x;

    if (blockIdx.x < NP1) {
        // ---------------- ball query 1: 1 wave per centroid ----------------
        const int s = blockIdx.x;
        const float* xb = xyz + (size_t)b*6*N1;
        const float* cp = new_xyz1 + ((size_t)b*NP1 + s)*3;
        float cx = cp[0], cy = cp[1], cz = cp[2];
        float snew = sumsq3(cx,cy,cz);
        int* out = idx1 + ((size_t)b*NP1 + s)*NS1;
        int cnt = 0, first = 0;
        for (int ch = 0; ch < N1/64; ++ch) {
            int n = ch*64 + lane;
            float x = xb[n], y = xb[N1+n], z = xb[2*N1+n];
            float sx  = sumsq3(x,y,z);
            float dt  = dot3(cx,cy,cz,x,y,z);
            float sqr = fsub(fadd(snew, sx), fmul(2.0f, dt));   // (|c|^2+|p|^2) - 2*dot
            bool inb = !(sqr > r2);
            unsigned long long mask = __ballot(inb);
            if (mask) {
                if (cnt == 0) first = ch*64 + (int)(__ffsll((unsigned long long)mask) - 1);
                if (inb) {
                    int pos = cnt + (int)__popcll(mask & ((1ull << lane) - 1ull));
                    if (pos < NS1) out[pos] = n;
                }
                cnt += (int)__popcll(mask);
                if (cnt >= NS1) break;
            }
        }
        int c = cnt < NS1 ? cnt : NS1;
        if (lane < NS1 && lane >= c) out[lane] = first;
    } else {
        // ---------------- fps2: 512 pts -> 256 picks, 1 wave per batch ----------------
        __shared__ float c3[N2*3];
        const int t = lane;
        const float* src = new_xyz1 + (size_t)b*N2*3;
        for (int e = t; e < N2*3; e += 64) c3[e] = src[e];
        __syncthreads();

        float px[8], py[8], pz[8], dd[8];
#pragma unroll
        for (int j = 0; j < 8; ++j) {
            int n = t + j*64;
            px[j] = c3[n*3]; py[j] = c3[n*3+1]; pz[j] = c3[n*3+2];
            dd[j] = 1e10f;
        }
        int cur = 0;
        for (int s = 0; s < NP2; ++s) {
            float cx = c3[cur*3], cy = c3[cur*3+1], cz = c3[cur*3+2];
            if (t == 0) {
                float* o = new_xyz2 + ((size_t)b*NP2 + s)*3;
                o[0]=cx; o[1]=cy; o[2]=cz;
                out0[b*3*NP2 + s]         = cx;   // l2_xyz transposed (8,3,256)
                out0[b*3*NP2 + NP2 + s]   = cy;
                out0[b*3*NP2 + 2*NP2 + s] = cz;
            }
            float bv = -1.0f; int bi = 0;
#pragma unroll
            for (int j = 0; j < 8; ++j) {
                float d  = dist3(px[j],py[j],pz[j],cx,cy,cz);
                float nd = fminf(dd[j], d);
                dd[j] = nd;
                int n = t + j*64;
                if (nd > bv) { bv = nd; bi = n; }
            }
            unsigned long long pk = ((unsigned long long)__float_as_uint(bv) << 9)
                                  | (unsigned long long)(511 - bi);
            pk = shflmax64(pk, 1);  pk = shflmax64(pk, 2);  pk = shflmax64(pk, 4);
            pk = shflmax64(pk, 8);  pk = shflmax64(pk, 16); pk = shflmax64(pk, 32);
            cur = 511 - (int)(pk & 511ull);
        }
    }
}

// =====================  FUSED: SA1 MLP (x < NP1, 256 thr)  +  ball query 2 (x >= NP1, 64 thr)  =====================
__global__ __launch_bounds__(256) void mlp1_ball2_kernel(const float* __restrict__ xyz,
    const float* __restrict__ new_xyz1, const int* __restrict__ idx1,
    const float* __restrict__ W1, const float* __restrict__ B1,
    const float* __restrict__ W2, const float* __restrict__ B2,
    const float* __restrict__ W3, const float* __restrict__ B3,
    float* __restrict__ l1_points,
    const float* __restrict__ new_xyz2, int* __restrict__ idx2, float r2b)
{
    const int b = blockIdx.y;
    const int t = threadIdx.x;

    if (blockIdx.x >= NP1) {
        // ---------------- ball query 2: first wave only ----------------
        if (t < 64) {
            const int s = blockIdx.x - NP1;
            const int lane = t;
            const float* pb = new_xyz1 + (size_t)b*N2*3;
            const float* cp = new_xyz2 + ((size_t)b*NP2 + s)*3;
            float cx = cp[0], cy = cp[1], cz = cp[2];
            float snew = sumsq3(cx,cy,cz);
            int* out = idx2 + ((size_t)b*NP2 + s)*NS2;
            int cnt = 0, first = 0;
            for (int ch = 0; ch < N2/64; ++ch) {
                int n = ch*64 + lane;
                float x = pb[n*3], y = pb[n*3+1], z = pb[n*3+2];
                float sx  = sumsq3(x,y,z);
                float dt  = dot3(cx,cy,cz,x,y,z);
                float sqr = fsub(fadd(snew, sx), fmul(2.0f, dt));
                bool inb = !(sqr > r2b);
                unsigned long long mask = __ballot(inb);
                if (mask) {
                    if (cnt == 0) first = ch*64 + (int)(__ffsll((unsigned long long)mask) - 1);
                    if (inb) {
                        int pos = cnt + (int)__popcll(mask & ((1ull << lane) - 1ull));
                        if (pos < NS2) out[pos] = n;
                    }
                    cnt += (int)__popcll(mask);
                    if (cnt >= NS2) break;
                }
            }
            int c = cnt < NS2 ? cnt : NS2;
            if (lane >= c) out[lane] = first;
        }
        return;
    }

    // ---------------- SA1 MLP (R6 known-good body) ----------------
    const int s = blockIdx.x;
    const float* xb = xyz + (size_t)b*6*N1;
    __shared__ __align__(16) float inb_[NS1][6];
    __shared__ __align__(16) float h1_[NS1][64];
    __shared__ __align__(16) float h2_[NS1][64];
    __shared__ __align__(16) float red_[2][128];
    __shared__ int sidx[NS1];

    const float* cp = new_xyz1 + ((size_t)b*NP1 + s)*3;
    float c0 = cp[0], c1 = cp[1], c2 = cp[2];
    if (t < NS1) sidx[t] = idx1[((size_t)b*NP1+s)*NS1 + t];
    __syncthreads();
    if (t < NS1*6) {
        int k = t / 6, c = t % 6;
        int n = sidx[k];
        float v = xb[(size_t)c*N1 + n];
        if (c == 0) v -= c0; else if (c == 1) v -= c1; else if (c == 2) v -= c2;
        inb_[k][c] = v;
    }
    __syncthreads();
    {   // L1
        int o = t & 63, kg = t >> 6;
        float w[6];
#pragma unroll
        for (int c = 0; c < 6; ++c) w[c] = W1[o*6+c];
        float bias = B1[o];
#pragma unroll
        for (int kk = 0; kk < 8; ++kk) {
            int k = kg*8 + kk;
            float a = 0.f;
#pragma unroll
            for (int c = 0; c < 6; ++c) a = fmaf(inb_[k][c], w[c], a);
            h1_[k][o] = fmaxf(a + bias, 0.f);
        }
    }
    __syncthreads();
    {   // L2: 64 -> 64
        int o = t & 63, kg = t >> 6;
        float acc[8] = {};
        for (int ch = 0; ch < 8; ++ch) {
            const float4 wa = *(const float4*)&W2[o*64 + ch*8];
            const float4 wbv = *(const float4*)&W2[o*64 + ch*8 + 4];
#pragma unroll
            for (int kk = 0; kk < 8; ++kk) {
                int k = kg*8+kk;
                const float4 a0 = *(const float4*)&h1_[k][ch*8];
                const float4 a1 = *(const float4*)&h1_[k][ch*8+4];
                acc[kk] = fmaf(a0.x, wa.x, acc[kk]);
                acc[kk] = fmaf(a0.y, wa.y, acc[kk]);
                acc[kk] = fmaf(a0.z, wa.z, acc[kk]);
                acc[kk] = fmaf(a0.w, wa.w, acc[kk]);
                acc[kk] = fmaf(a1.x, wbv.x, acc[kk]);
                acc[kk] = fmaf(a1.y, wbv.y, acc[kk]);
                acc[kk] = fmaf(a1.z, wbv.z, acc[kk]);
                acc[kk] = fmaf(a1.w, wbv.w, acc[kk]);
            }
        }
        float bias = B2[o];
#pragma unroll
        for (int kk = 0; kk < 8; ++kk) h2_[kg*8+kk][o] = fmaxf(acc[kk] + bias, 0.f);
    }
    __syncthreads();
    {   // L3: 64 -> 128 + max over samples
        int o = t & 127, kg = t >> 7;
        float acc[16] = {};
        for (int ch = 0; ch < 8; ++ch) {
            const float4 wa = *(const float4*)&W3[o*64 + ch*8];
            const float4 wbv = *(const float4*)&W3[o*64 + ch*8 + 4];
#pragma unroll
            for (int kk = 0; kk < 16; ++kk) {
                int k = kg*16+kk;
                const float4 a0 = *(const float4*)&h2_[k][ch*8];
                const float4 a1 = *(const float4*)&h2_[k][ch*8+4];
                acc[kk] = fmaf(a0.x, wa.x, acc[kk]);
                acc[kk] = fmaf(a0.y, wa.y, acc[kk]);
                acc[kk] = fmaf(a0.z, wa.z, acc[kk]);
                acc[kk] = fmaf(a0.w, wa.w, acc[kk]);
                acc[kk] = fmaf(a1.x, wbv.x, acc[kk]);
                acc[kk] = fmaf(a1.y, wbv.y, acc[kk]);
                acc[kk] = fmaf(a1.z, wbv.z, acc[kk]);
                acc[kk] = fmaf(a1.w, wbv.w, acc[kk]);
            }
        }
        float bias = B3[o];
        float m = -1e30f;
#pragma unroll
        for (int kk = 0; kk < 16; ++kk) m = fmaxf(m, fmaxf(acc[kk] + bias, 0.f));
        red_[kg][o] = m;
    }
    __syncthreads();
    if (t < 128) {
        float m = fmaxf(red_[0][t], red_[1][t]);
        l1_points[((size_t)b*NP1+s)*128 + t] = m;   // (b, n, 128) layout
    }
}

// =====================  SA2 MLP (131->128->128->285) + maxpool over 64  =====================
// R6 version (frozen): feature-major LDS layout, float4 staging + float4
// LDS reads; L1/L2 compute 2 outputs/thread. Two sample-halves, < 64 KB LDS.
__global__ __launch_bounds__(256) void mlp2_kernel(
    const float* __restrict__ new_xyz1, const float* __restrict__ l1_points,
    const float* __restrict__ new_xyz2, const int* __restrict__ idx2,
    const float* __restrict__ W1, const float* __restrict__ B1,
    const float* __restrict__ W2, const float* __restrict__ B2,
    const float* __restrict__ W3, const float* __restrict__ B3,
    float* __restrict__ out1)
{
    const int s = blockIdx.x, b = blockIdx.y;
    const int t = threadIdx.x;
    __shared__ __align__(16) float inb_[32][132];   // 132 = pad to 16B rows
    __shared__ __align__(16) float h1_[32][128];
    __shared__ __align__(16) float h2_[32][128];
    __shared__ int sidx[NS2];

    const float* cp = new_xyz2 + ((size_t)b*NP2+s)*3;
    float c0=cp[0], c1=cp[1], c2=cp[2];
    if (t < NS2) sidx[t] = idx2[((size_t)b*NP2+s)*NS2 + t];

    const int o1 = t & 63, o2 = o1 + 64, g = t >> 6;   // L1/L2 mapping
    float vmax0 = -1e30f, vmax1 = -1e30f;              // L3: o=t and o=t+256

    for (int half = 0; half < 2; ++half) {
        __syncthreads();
        // stage: features via float4, then 3 relative coords
        for (int e = t; e < 32*32; e += 256) {
            int kk = e >> 5, c4 = e & 31;
            int n = sidx[half*32 + kk];
            *(float4*)&inb_[kk][c4*4] =
                *(const float4*)&l1_points[((size_t)b*N2 + n)*128 + c4*4];
        }
        for (int e = t; e < 32*3; e += 256) {
            int kk = e / 3, c = e % 3;
            int n = sidx[half*32 + kk];
            inb_[kk][128 + c] = new_xyz1[((size_t)b*N2 + n)*3 + c]
                              - (c==0 ? c0 : (c==1 ? c1 : c2));
        }
        __syncthreads();
        {   // L1: 131 -> 128, 2 outputs x 8 samples per thread
            float accA[8] = {}, accB[8] = {};
            for (int ch = 0; ch < 16; ++ch) {
                float wa[8], wbv[8];
#pragma unroll
                for (int j = 0; j < 8; ++j) {
                    wa[j]  = W1[o1*131 + 3 + ch*8 + j];   // feature cols are W1 cols 3..130
                    wbv[j] = W1[o2*131 + 3 + ch*8 + j];
                }
#pragma unroll
                for (int kk = 0; kk < 8; ++kk) {
                    int k = g*8 + kk;
                    const float4 a0 = *(const float4*)&inb_[k][ch*8];
                    const float4 a1 = *(const float4*)&inb_[k][ch*8+4];
                    accA[kk] = fmaf(a0.x, wa[0], accA[kk]);
                    accA[kk] = fmaf(a0.y, wa[1], accA[kk]);
                    accA[kk] = fmaf(a0.z, wa[2], accA[kk]);
                    accA[kk] = fmaf(a0.w, wa[3], accA[kk]);
                    accA[kk] = fmaf(a1.x, wa[4], accA[kk]);
                    accA[kk] = fmaf(a1.y, wa[5], accA[kk]);
                    accA[kk] = fmaf(a1.z, wa[6], accA[kk]);
                    accA[kk] = fmaf(a1.w, wa[7], accA[kk]);
                    accB[kk] = fmaf(a0.x, wbv[0], accB[kk]);
                    accB[kk] = fmaf(a0.y, wbv[1], accB[kk]);
                    accB[kk] = fmaf(a0.z, wbv[2], accB[kk]);
                    accB[kk] = fmaf(a0.w, wbv[3], accB[kk]);
                    accB[kk] = fmaf(a1.x, wbv[4], accB[kk]);
                    accB[kk] = fmaf(a1.y, wbv[5], accB[kk]);
                    accB[kk] = fmaf(a1.z, wbv[6], accB[kk]);
                    accB[kk] = fmaf(a1.w, wbv[7], accB[kk]);
                }
            }
            // coord tail (W1 cols 0..2)
            float ta0=W1[o1*131+0], ta1=W1[o1*131+1], ta2=W1[o1*131+2];
            float tb0=W1[o2*131+0], tb1=W1[o2*131+1], tb2=W1[o2*131+2];
            float biasA = B1[o1], biasB = B1[o2];
#pragma unroll
            for (int kk = 0; kk < 8; ++kk) {
                int k = g*8 + kk;
                float f0 = inb_[k][128], f1 = inb_[k][129], f2 = inb_[k][130];
                float vA = accA[kk];
                vA = fmaf(f0, ta0, vA); vA = fmaf(f1, ta1, vA); vA = fmaf(f2, ta2, vA);
                float vB = accB[kk];
                vB = fmaf(f0, tb0, vB); vB = fmaf(f1, tb1, vB); vB = fmaf(f2, tb2, vB);
                h1_[k][o1] = fmaxf(vA + biasA, 0.f);
                h1_[k][o2] = fmaxf(vB + biasB, 0.f);
            }
        }
        __syncthreads();
        {   // L2: 128 -> 128, 2 outputs x 8 samples per thread
            float accA[8] = {}, accB[8] = {};
            for (int ch = 0; ch < 16; ++ch) {
                const float4 wa0 = *(const float4*)&W2[o1*128 + ch*8];
                const float4 wa1 = *(const float4*)&W2[o1*128 + ch*8 + 4];
                const float4 wb0 = *(const float4*)&W2[o2*128 + ch*8];
                const float4 wb1 = *(const float4*)&W2[o2*128 + ch*8 + 4];
#pragma unroll
                for (int kk = 0; kk < 8; ++kk) {
                    int k = g*8 + kk;
                    const float4 a0 = *(const float4*)&h1_[k][ch*8];
                    const float4 a1 = *(const float4*)&h1_[k][ch*8+4];
                    accA[kk] = fmaf(a0.x, wa0.x, accA[kk]);
                    accA[kk] = fmaf(a0.y, wa0.y, accA[kk]);
                    accA[kk] = fmaf(a0.z, wa0.z, accA[kk]);
                    accA[kk] = fmaf(a0.w, wa0.w, accA[kk]);
                    accA[kk] = fmaf(a1.x, wa1.x, accA[kk]);
                    accA[kk] = fmaf(a1.y, wa1.y, accA[kk]);
                    accA[kk] = fmaf(a1.z, wa1.z, accA[kk]);
                    accA[kk] = fmaf(a1.w, wa1.w, accA[kk]);
                    accB[kk] = fmaf(a0.x, wb0.x, accB[kk]);
                    accB[kk] = fmaf(a0.y, wb0.y, accB[kk]);
                    accB[kk] = fmaf(a0.z, wb0.z, accB[kk]);
                    accB[kk] = fmaf(a0.w, wb0.w, accB[kk]);
                    accB[kk] = fmaf(a1.x, wb1.x, accB[kk]);
                    accB[kk] = fmaf(a1.y, wb1.y, accB[kk]);
                    accB[kk] = fmaf(a1.z, wb1.z, accB[kk]);
                    accB[kk] = fmaf(a1.w, wb1.w, accB[kk]);
                }
            }
            float biasA = B2[o1], biasB = B2[o2];
#pragma unroll
            for (int kk = 0; kk < 8; ++kk) {
                int k = g*8 + kk;
                h2_[k][o1] = fmaxf(accA[kk] + biasA, 0.f);
                h2_[k][o2] = fmaxf(accB[kk] + biasB, 0.f);
            }
        }
        __syncthreads();
        {   // L3: 128 -> 285, fold max over this half's 32 samples
            {
                float acc[32] = {};
                for (int ch = 0; ch < 16; ++ch) {
                    const float4 w0 = *(const float4*)&W3[t*128 + ch*8];
                    const float4 w1 = *(const float4*)&W3[t*128 + ch*8 + 4];
#pragma unroll
                    for (int kk = 0; kk < 32; ++kk) {
                        const float4 a0 = *(const float4*)&h2_[kk][ch*8];
                        const float4 a1 = *(const float4*)&h2_[kk][ch*8+4];
                        acc[kk] = fmaf(a0.x, w0.x, acc[kk]);
                        acc[kk] = fmaf(a0.y, w0.y, acc[kk]);
                        acc[kk] = fmaf(a0.z, w0.z, acc[kk]);
                        acc[kk] = fmaf(a0.w, w0.w, acc[kk]);
                        acc[kk] = fmaf(a1.x, w1.x, acc[kk]);
                        acc[kk] = fmaf(a1.y, w1.y, acc[kk]);
                        acc[kk] = fmaf(a1.z, w1.z, acc[kk]);
                        acc[kk] = fmaf(a1.w, w1.w, acc[kk]);
                    }
                }
                float bias = B3[t];
                float mm = vmax0;
#pragma unroll
                for (int kk = 0; kk < 32; ++kk) mm = fmaxf(mm, fmaxf(acc[kk] + bias, 0.f));
                vmax0 = mm;
            }
            if (t < 29) {
                int o = t + 256;
                float acc[32] = {};
                for (int ch = 0; ch < 16; ++ch) {
                    const float4 w0 = *(const float4*)&W3[o*128 + ch*8];
                    const float4 w1 = *(const float4*)&W3[o*128 + ch*8 + 4];
#pragma unroll
                    for (int kk = 0; kk < 32; ++kk) {
                        const float4 a0 = *(const float4*)&h2_[kk][ch*8];
                        const float4 a1 = *(const float4*)&h2_[kk][ch*8+4];
                        acc[kk] = fmaf(a0.x, w0.x, acc[kk]);
                        acc[kk] = fmaf(a0.y, w0.y, acc[kk]);
                        acc[kk] = fmaf(a0.z, w0.z, acc[kk]);
                        acc[kk] = fmaf(a0.w, w0.w, acc[kk]);
                        acc[kk] = fmaf(a1.x, w1.x, acc[kk]);
                        acc[kk] = fmaf(a1.y, w1.y, acc[kk]);
                        acc[kk] = fmaf(a1.z, w1.z, acc[kk]);
                        acc[kk] = fmaf(a1.w, w1.w, acc[kk]);
                    }
                }
                float bias = B3[o];
                float mm = vmax1;
#pragma unroll
                for (int kk = 0; kk < 32; ++kk) mm = fmaxf(mm, fmaxf(acc[kk] + bias, 0.f));
                vmax1 = mm;
            }
        }
    }
    out1[((size_t)b*NP2+s)*285 + t] = vmax0;
    if (t < 29) out1[((size_t)b*NP2+s)*285 + t + 256] = vmax1;
}

extern "C" void kernel_launch(void* const* d_in, const int* in_sizes, int n_in,
                              void* d_out, int out_size, void* d_ws, size_t ws_size,
                              hipStream_t stream)
{
    (void)in_sizes; (void)n_in; (void)out_size; (void)ws_size;
    const float* xyz  = (const float*)d_in[0];
    const float* s1w1 = (const float*)d_in[1];  const float* s1b1 = (const float*)d_in[2];
    const float* s1w2 = (const float*)d_in[3];  const float* s1b2 = (const float*)d_in[4];
    const float* s1w3 = (const float*)d_in[5];  const float* s1b3 = (const float*)d_in[6];
    const float* s2w1 = (const float*)d_in[7];  const float* s2b1 = (const float*)d_in[8];
    const float* s2w2 = (const float*)d_in[9];  const float* s2b2 = (const float*)d_in[10];
    const float* s2w3 = (const float*)d_in[11]; const float* s2b3 = (const float*)d_in[12];

    float* ws        = (float*)d_ws;
    float* new_xyz1  = ws;                  // 8*512*3   = 12288 f
    float* new_xyz2  = ws + 12288;          // 8*256*3   = 6144 f
    float* l1_points = ws + 18432;          // 8*512*128 = 524288 f
    int*   idx1      = (int*)(ws + 542720); // 8*512*32  = 131072 i
    int*   idx2      = idx1 + 131072;       // 8*256*64  = 131072 i
    // fps1 exchange slots: 8 batches x 2 parities x 16 blocks u64 (2 KB)
    unsigned long long* bests = (unsigned long long*)(ws + 804864);

    float* out0 = (float*)d_out;            // (8,3,256)
    float* out1 = out0 + 8*3*256;           // (8,256,285)

    const float r2a = (float)(0.025*0.025);
    const float r2b = (float)(0.05*0.05);

    fps1_kernel      <<<dim3(FPS1_M, 8),    dim3(FPS1_TB), 0, stream>>>(xyz, new_xyz1, bests);
    ball1_fps2_kernel<<<dim3(NP1+1, 8),     dim3(64),      0, stream>>>(xyz, new_xyz1, idx1, r2a,
                         new_xyz2, out0);
    mlp1_ball2_kernel<<<dim3(NP1+NP2, 8),   dim3(256),     0, stream>>>(xyz, new_xyz1, idx1,
                         s1w1,s1b1,s1w2,s1b2,s1w3,s1b3, l1_points,
                         new_xyz2, idx2, r2b);
    mlp2_kernel      <<<dim3(NP2, 8),       dim3(256),     0, stream>>>(new_xyz1, l1_points,
                         new_xyz2, idx2, s2w1,s2b1,s2w2,s2b2,s2w3,s2b3, out1);
}

// Round 11
// 1791.637 us; speedup vs baseline: 1.2036x; 1.2036x over previous
//
#include <hip/hip_runtime.h>

#define N1 32768
#define NP1 512
#define NS1 32
#define N2 512
#define NP2 256
#define NS2 64
#define POISON 0xAAAAAAAAu

// ---- exact-rounding helpers: replicate reference op-by-op (NO fma/contract) ----
__device__ __forceinline__ float fadd(float a, float b){ return __fadd_rn(a,b); }
__device__ __forceinline__ float fmul(float a, float b){ return __fmul_rn(a,b); }
__device__ __forceinline__ float fsub(float a, float b){ return __fsub_rn(a,b); }

__device__ __forceinline__ float dist3(float px,float py,float pz,float cx,float cy,float cz){
    float dx = fsub(px,cx), dy = fsub(py,cy), dz = fsub(pz,cz);
    return fadd(fadd(fmul(dx,dx), fmul(dy,dy)), fmul(dz,dz));
}
__device__ __forceinline__ float sumsq3(float x,float y,float z){
    return fadd(fadd(fmul(x,x), fmul(y,y)), fmul(z,z));
}
__device__ __forceinline__ float dot3(float ax,float ay,float az,float bx,float by,float bz){
    return fadd(fadd(fmul(ax,bx), fmul(ay,by)), fmul(az,bz));
}

__device__ __forceinline__ unsigned long long shflmax64(unsigned long long k, int off){
    unsigned long long o = __shfl_xor(k, off, 64);
    return o > k ? o : k;
}

// =====================  MEGA STAGE 1: fps1 + ball1 + fps2 in one grid  =====================
// x in [0,16):   fps1 chunk blocks (R6-exact exchange, proven stable 1020us,
//                centroids published via agent-scope atomic stores)
// x in [16,144): ball1, 4 centroids/block (1/wave); each wave value-polls its
//                centroid (poison 0xAA bits impossible for [0,1) coords),
//                lane-0 poll + s_sleep + shuffle broadcast -> runs in fps1's
//                shadow instead of serially after it
// x == 144:      fps2 (stages new_xyz1 with per-element poison polling)
#define FPS1_M  16
#define ST1_X   (FPS1_M + NP1/4 + 1)   // 145

__global__ __launch_bounds__(256) void stage1_kernel(const float* __restrict__ xyz,
                                                     float* __restrict__ new_xyz1,
                                                     unsigned long long* __restrict__ bests,
                                                     int* __restrict__ idx1, float r2,
                                                     float* __restrict__ new_xyz2,
                                                     float* __restrict__ out0)
{
    const int x = blockIdx.x;
    const int b = blockIdx.y;
    const int t = threadIdx.x;
    const int lane = t & 63;
    const int wid  = t >> 6;
    const float* xb = xyz + (size_t)b * 6 * N1;

    if (x < FPS1_M) {
        // ---------------- fps1 (R6-exact body) ----------------
        const int m = x;
        __shared__ unsigned long long wb[4];
        __shared__ float cw[4];

        const int base = m * (N1 / FPS1_M);   // 2048-pt chunk
        float px[8], py[8], pz[8], dd[8];
#pragma unroll
        for (int j = 0; j < 8; ++j) {
            int n = base + t + j * 256;
            px[j] = xb[n];
            py[j] = xb[N1 + n];
            pz[j] = xb[2*N1 + n];
            dd[j] = 1e10f;
        }

        float cx = xb[0], cy = xb[N1], cz = xb[2*N1];   // first pick = index 0

        for (int s = 0; s < NP1; ++s) {
            if (m == 0 && t == 0) {
                unsigned* o = (unsigned*)(new_xyz1 + ((size_t)b*NP1 + s)*3);
                __hip_atomic_store(o+0, __float_as_uint(cx), __ATOMIC_RELAXED, __HIP_MEMORY_SCOPE_AGENT);
                __hip_atomic_store(o+1, __float_as_uint(cy), __ATOMIC_RELAXED, __HIP_MEMORY_SCOPE_AGENT);
                __hip_atomic_store(o+2, __float_as_uint(cz), __ATOMIC_RELAXED, __HIP_MEMORY_SCOPE_AGENT);
            }
            if (s == NP1 - 1) break;

            // update min-dists, in-thread argmax (ascending n -> first-max kept)
            float bv = -1.0f; int bi = base + t;
#pragma unroll
            for (int j = 0; j < 8; ++j) {
                float d  = dist3(px[j],py[j],pz[j],cx,cy,cz);
                float nd = fminf(dd[j], d);
                dd[j] = nd;
                if (nd > bv) { bv = nd; bi = base + t + j*256; }
            }
            // packed key: float bits order-isomorphic (dist>=0); tie -> min index
            unsigned long long pk = ((unsigned long long)__float_as_uint(bv) << 15)
                                  | (unsigned long long)(32767 - bi);
            pk = shflmax64(pk, 1);  pk = shflmax64(pk, 2);  pk = shflmax64(pk, 4);
            pk = shflmax64(pk, 8);  pk = shflmax64(pk, 16); pk = shflmax64(pk, 32);
            if (lane == 0) wb[wid] = pk;
            __syncthreads();

            if (wid == 0) {
                unsigned long long k4 = (lane < 4) ? wb[lane] : 0ull;
                k4 = shflmax64(k4, 1); k4 = shflmax64(k4, 2);
                unsigned long long* slotPar = bests + ((size_t)b*2 + (s & 1))*FPS1_M;
                if (lane == 0)
                    __hip_atomic_store(slotPar + m, (k4 << 10) | (unsigned long long)s,
                                       __ATOMIC_RELAXED, __HIP_MEMORY_SCOPE_AGENT);
                // parallel poll: lane q watches slot q; speculative centroid load
                unsigned long long myv = 0; bool done = (lane >= FPS1_M);
                float ccx = 0.f, ccy = 0.f, ccz = 0.f;
                while (__ballot(done) != 0xFFFFFFFFFFFFFFFFull) {
                    if (!done) {
                        unsigned long long v = __hip_atomic_load(slotPar + lane,
                                                 __ATOMIC_RELAXED, __HIP_MEMORY_SCOPE_AGENT);
                        if ((unsigned)(v & 1023ull) == (unsigned)s) {
                            done = true; myv = v;
                            int idx = 32767 - (int)((v >> 10) & 0x7fffull);
                            ccx = xb[idx]; ccy = xb[N1 + idx]; ccz = xb[2*N1 + idx];
                        }
                    }
                }
                unsigned long long w = myv;
                w = shflmax64(w, 1); w = shflmax64(w, 2); w = shflmax64(w, 4); w = shflmax64(w, 8);
                int wl = (int)__ffsll(__ballot(myv == w)) - 1;   // keys unique
                float ncx = __shfl(ccx, wl, 64);
                float ncy = __shfl(ccy, wl, 64);
                float ncz = __shfl(ccz, wl, 64);
                if (lane == 0) { cw[0] = ncx; cw[1] = ncy; cw[2] = ncz; }
            }
            __syncthreads();
            cx = cw[0]; cy = cw[1]; cz = cw[2];
        }
        return;
    }

    if (x < FPS1_M + NP1/4) {
        // ---------------- ball1: 1 wave per centroid, 4 centroids/block ----------------
        const int s = (x - FPS1_M)*4 + wid;
        // value-poll the centroid: 0xAA poison bits are impossible for [0,1) coords
        unsigned ux = 0, uy = 0, uz = 0;
        if (lane == 0) {
            const unsigned* cp = (const unsigned*)(new_xyz1 + ((size_t)b*NP1 + s)*3);
            for (;;) {
                ux = __hip_atomic_load(cp+0, __ATOMIC_RELAXED, __HIP_MEMORY_SCOPE_AGENT);
                uy = __hip_atomic_load(cp+1, __ATOMIC_RELAXED, __HIP_MEMORY_SCOPE_AGENT);
                uz = __hip_atomic_load(cp+2, __ATOMIC_RELAXED, __HIP_MEMORY_SCOPE_AGENT);
                if (ux != POISON && uy != POISON && uz != POISON) break;
                __builtin_amdgcn_s_sleep(32);
            }
        }
        float cx = __uint_as_float(__shfl((int)ux, 0, 64));
        float cy = __uint_as_float(__shfl((int)uy, 0, 64));
        float cz = __uint_as_float(__shfl((int)uz, 0, 64));

        float snew = sumsq3(cx,cy,cz);
        int* out = idx1 + ((size_t)b*NP1 + s)*NS1;
        int cnt = 0, first = 0;
        for (int ch = 0; ch < N1/64; ++ch) {
            int n = ch*64 + lane;
            float px_ = xb[n], py_ = xb[N1+n], pz_ = xb[2*N1+n];
            float sx  = sumsq3(px_,py_,pz_);
            float dt  = dot3(cx,cy,cz,px_,py_,pz_);
            float sqr = fsub(fadd(snew, sx), fmul(2.0f, dt));   // (|c|^2+|p|^2) - 2*dot
            bool inb = !(sqr > r2);
            unsigned long long mask = __ballot(inb);
            if (mask) {
                if (cnt == 0) first = ch*64 + (int)(__ffsll((unsigned long long)mask) - 1);
                if (inb) {
                    int pos = cnt + (int)__popcll(mask & ((1ull << lane) - 1ull));
                    if (pos < NS1) out[pos] = n;
                }
                cnt += (int)__popcll(mask);
                if (cnt >= NS1) break;
            }
        }
        int c = cnt < NS1 ? cnt : NS1;
        if (lane < NS1 && lane >= c) out[lane] = first;
        return;
    }

    // ---------------- fps2: stage with poison polling, then 1-wave FPS ----------------
    {
        __shared__ float c3[N2*3];
        const float* src = new_xyz1 + (size_t)b*N2*3;
        for (int e = t; e < N2*3; e += 256) {
            const unsigned* sp = (const unsigned*)(src + e);
            unsigned v;
            for (;;) {
                v = __hip_atomic_load(sp, __ATOMIC_RELAXED, __HIP_MEMORY_SCOPE_AGENT);
                if (v != POISON) break;
                __builtin_amdgcn_s_sleep(32);
            }
            c3[e] = __uint_as_float(v);
        }
        __syncthreads();
        if (t >= 64) return;

        float px[8], py[8], pz[8], dd[8];
#pragma unroll
        for (int j = 0; j < 8; ++j) {
            int n = t + j*64;
            px[j] = c3[n*3]; py[j] = c3[n*3+1]; pz[j] = c3[n*3+2];
            dd[j] = 1e10f;
        }
        int cur = 0;
        for (int s = 0; s < NP2; ++s) {
            float cx = c3[cur*3], cy = c3[cur*3+1], cz = c3[cur*3+2];
            if (t == 0) {
                float* o = new_xyz2 + ((size_t)b*NP2 + s)*3;
                o[0]=cx; o[1]=cy; o[2]=cz;
                out0[b*3*NP2 + s]         = cx;   // l2_xyz transposed (8,3,256)
                out0[b*3*NP2 + NP2 + s]   = cy;
                out0[b*3*NP2 + 2*NP2 + s] = cz;
            }
            float bv = -1.0f; int bi = 0;
#pragma unroll
            for (int j = 0; j < 8; ++j) {
                float d  = dist3(px[j],py[j],pz[j],cx,cy,cz);
                float nd = fminf(dd[j], d);
                dd[j] = nd;
                int n = t + j*64;
                if (nd > bv) { bv = nd; bi = n; }
            }
            unsigned long long pk = ((unsigned long long)__float_as_uint(bv) << 9)
                                  | (unsigned long long)(511 - bi);
            pk = shflmax64(pk, 1);  pk = shflmax64(pk, 2);  pk = shflmax64(pk, 4);
            pk = shflmax64(pk, 8);  pk = shflmax64(pk, 16); pk = shflmax64(pk, 32);
            cur = 511 - (int)(pk & 511ull);
        }
    }
}

// =====================  FUSED: SA1 MLP (x < NP1, 256 thr)  +  ball query 2 (x >= NP1, 64 thr)  =====================
__global__ __launch_bounds__(256) void mlp1_ball2_kernel(const float* __restrict__ xyz,
    const float* __restrict__ new_xyz1, const int* __restrict__ idx1,
    const float* __restrict__ W1, const float* __restrict__ B1,
    const float* __restrict__ W2, const float* __restrict__ B2,
    const float* __restrict__ W3, const float* __restrict__ B3,
    float* __restrict__ l1_points,
    const float* __restrict__ new_xyz2, int* __restrict__ idx2, float r2b)
{
    const int b = blockIdx.y;
    const int t = threadIdx.x;

    if (blockIdx.x >= NP1) {
        // ---------------- ball query 2: first wave only ----------------
        if (t < 64) {
            const int s = blockIdx.x - NP1;
            const int lane = t;
            const float* pb = new_xyz1 + (size_t)b*N2*3;
            const float* cp = new_xyz2 + ((size_t)b*NP2 + s)*3;
            float cx = cp[0], cy = cp[1], cz = cp[2];
            float snew = sumsq3(cx,cy,cz);
            int* out = idx2 + ((size_t)b*NP2 + s)*NS2;
            int cnt = 0, first = 0;
            for (int ch = 0; ch < N2/64; ++ch) {
                int n = ch*64 + lane;
                float x = pb[n*3], y = pb[n*3+1], z = pb[n*3+2];
                float sx  = sumsq3(x,y,z);
                float dt  = dot3(cx,cy,cz,x,y,z);
                float sqr = fsub(fadd(snew, sx), fmul(2.0f, dt));
                bool inb = !(sqr > r2b);
                unsigned long long mask = __ballot(inb);
                if (mask) {
                    if (cnt == 0) first = ch*64 + (int)(__ffsll((unsigned long long)mask) - 1);
                    if (inb) {
                        int pos = cnt + (int)__popcll(mask & ((1ull << lane) - 1ull));
                        if (pos < NS2) out[pos] = n;
                    }
                    cnt += (int)__popcll(mask);
                    if (cnt >= NS2) break;
                }
            }
            int c = cnt < NS2 ? cnt : NS2;
            if (lane >= c) out[lane] = first;
        }
        return;
    }

    // ---------------- SA1 MLP (R6 known-good body) ----------------
    const int s = blockIdx.x;
    const float* xb = xyz + (size_t)b*6*N1;
    __shared__ __align__(16) float inb_[NS1][6];
    __shared__ __align__(16) float h1_[NS1][64];
    __shared__ __align__(16) float h2_[NS1][64];
    __shared__ __align__(16) float red_[2][128];
    __shared__ int sidx[NS1];

    const float* cp = new_xyz1 + ((size_t)b*NP1 + s)*3;
    float c0 = cp[0], c1 = cp[1], c2 = cp[2];
    if (t < NS1) sidx[t] = idx1[((size_t)b*NP1+s)*NS1 + t];
    __syncthreads();
    if (t < NS1*6) {
        int k = t / 6, c = t % 6;
        int n = sidx[k];
        float v = xb[(size_t)c*N1 + n];
        if (c == 0) v -= c0; else if (c == 1) v -= c1; else if (c == 2) v -= c2;
        inb_[k][c] = v;
    }
    __syncthreads();
    {   // L1
        int o = t & 63, kg = t >> 6;
        float w[6];
#pragma unroll
        for (int c = 0; c < 6; ++c) w[c] = W1[o*6+c];
        float bias = B1[o];
#pragma unroll
        for (int kk = 0; kk < 8; ++kk) {
            int k = kg*8 + kk;
            float a = 0.f;
#pragma unroll
            for (int c = 0; c < 6; ++c) a = fmaf(inb_[k][c], w[c], a);
            h1_[k][o] = fmaxf(a + bias, 0.f);
        }
    }
    __syncthreads();
    {   // L2: 64 -> 64
        int o = t & 63, kg = t >> 6;
        float acc[8] = {};
        for (int ch = 0; ch < 8; ++ch) {
            const float4 wa = *(const float4*)&W2[o*64 + ch*8];
            const float4 wbv = *(const float4*)&W2[o*64 + ch*8 + 4];
#pragma unroll
            for (int kk = 0; kk < 8; ++kk) {
                int k = kg*8+kk;
                const float4 a0 = *(const float4*)&h1_[k][ch*8];
                const float4 a1 = *(const float4*)&h1_[k][ch*8+4];
                acc[kk] = fmaf(a0.x, wa.x, acc[kk]);
                acc[kk] = fmaf(a0.y, wa.y, acc[kk]);
                acc[kk] = fmaf(a0.z, wa.z, acc[kk]);
                acc[kk] = fmaf(a0.w, wa.w, acc[kk]);
                acc[kk] = fmaf(a1.x, wbv.x, acc[kk]);
                acc[kk] = fmaf(a1.y, wbv.y, acc[kk]);
                acc[kk] = fmaf(a1.z, wbv.z, acc[kk]);
                acc[kk] = fmaf(a1.w, wbv.w, acc[kk]);
            }
        }
        float bias = B2[o];
#pragma unroll
        for (int kk = 0; kk < 8; ++kk) h2_[kg*8+kk][o] = fmaxf(acc[kk] + bias, 0.f);
    }
    __syncthreads();
    {   // L3: 64 -> 128 + max over samples
        int o = t & 127, kg = t >> 7;
        float acc[16] = {};
        for (int ch = 0; ch < 8; ++ch) {
            const float4 wa = *(const float4*)&W3[o*64 + ch*8];
            const float4 wbv = *(const float4*)&W3[o*64 + ch*8 + 4];
#pragma unroll
            for (int kk = 0; kk < 16; ++kk) {
                int k = kg*16+kk;
                const float4 a0 = *(const float4*)&h2_[k][ch*8];
                const float4 a1 = *(const float4*)&h2_[k][ch*8+4];
                acc[kk] = fmaf(a0.x, wa.x, acc[kk]);
                acc[kk] = fmaf(a0.y, wa.y, acc[kk]);
                acc[kk] = fmaf(a0.z, wa.z, acc[kk]);
                acc[kk] = fmaf(a0.w, wa.w, acc[kk]);
                acc[kk] = fmaf(a1.x, wbv.x, acc[kk]);
                acc[kk] = fmaf(a1.y, wbv.y, acc[kk]);
                acc[kk] = fmaf(a1.z, wbv.z, acc[kk]);
                acc[kk] = fmaf(a1.w, wbv.w, acc[kk]);
            }
        }
        float bias = B3[o];
        float m = -1e30f;
#pragma unroll
        for (int kk = 0; kk < 16; ++kk) m = fmaxf(m, fmaxf(acc[kk] + bias, 0.f));
        red_[kg][o] = m;
    }
    __syncthreads();
    if (t < 128) {
        float m = fmaxf(red_[0][t], red_[1][t]);
        l1_points[((size_t)b*NP1+s)*128 + t] = m;   // (b, n, 128) layout
    }
}

// =====================  SA2 MLP (131->128->128->285) + maxpool over 64  =====================
// R6 version (frozen): feature-major LDS layout, float4 staging + float4
// LDS reads; L1/L2 compute 2 outputs/thread. Two sample-halves, < 64 KB LDS.
__global__ __launch_bounds__(256) void mlp2_kernel(
    const float* __restrict__ new_xyz1, const float* __restrict__ l1_points,
    const float* __restrict__ new_xyz2, const int* __restrict__ idx2,
    const float* __restrict__ W1, const float* __restrict__ B1,
    const float* __restrict__ W2, const float* __restrict__ B2,
    const float* __restrict__ W3, const float* __restrict__ B3,
    float* __restrict__ out1)
{
    const int s = blockIdx.x, b = blockIdx.y;
    const int t = threadIdx.x;
    __shared__ __align__(16) float inb_[32][132];   // 132 = pad to 16B rows
    __shared__ __align__(16) float h1_[32][128];
    __shared__ __align__(16) float h2_[32][128];
    __shared__ int sidx[NS2];

    const float* cp = new_xyz2 + ((size_t)b*NP2+s)*3;
    float c0=cp[0], c1=cp[1], c2=cp[2];
    if (t < NS2) sidx[t] = idx2[((size_t)b*NP2+s)*NS2 + t];

    const int o1 = t & 63, o2 = o1 + 64, g = t >> 6;   // L1/L2 mapping
    float vmax0 = -1e30f, vmax1 = -1e30f;              // L3: o=t and o=t+256

    for (int half = 0; half < 2; ++half) {
        __syncthreads();
        // stage: features via float4, then 3 relative coords
        for (int e = t; e < 32*32; e += 256) {
            int kk = e >> 5, c4 = e & 31;
            int n = sidx[half*32 + kk];
            *(float4*)&inb_[kk][c4*4] =
                *(const float4*)&l1_points[((size_t)b*N2 + n)*128 + c4*4];
        }
        for (int e = t; e < 32*3; e += 256) {
            int kk = e / 3, c = e % 3;
            int n = sidx[half*32 + kk];
            inb_[kk][128 + c] = new_xyz1[((size_t)b*N2 + n)*3 + c]
                              - (c==0 ? c0 : (c==1 ? c1 : c2));
        }
        __syncthreads();
        {   // L1: 131 -> 128, 2 outputs x 8 samples per thread
            float accA[8] = {}, accB[8] = {};
            for (int ch = 0; ch < 16; ++ch) {
                float wa[8], wbv[8];
#pragma unroll
                for (int j = 0; j < 8; ++j) {
                    wa[j]  = W1[o1*131 + 3 + ch*8 + j];   // feature cols are W1 cols 3..130
                    wbv[j] = W1[o2*131 + 3 + ch*8 + j];
                }
#pragma unroll
                for (int kk = 0; kk < 8; ++kk) {
                    int k = g*8 + kk;
                    const float4 a0 = *(const float4*)&inb_[k][ch*8];
                    const float4 a1 = *(const float4*)&inb_[k][ch*8+4];
                    accA[kk] = fmaf(a0.x, wa[0], accA[kk]);
                    accA[kk] = fmaf(a0.y, wa[1], accA[kk]);
                    accA[kk] = fmaf(a0.z, wa[2], accA[kk]);
                    accA[kk] = fmaf(a0.w, wa[3], accA[kk]);
                    accA[kk] = fmaf(a1.x, wa[4], accA[kk]);
                    accA[kk] = fmaf(a1.y, wa[5], accA[kk]);
                    accA[kk] = fmaf(a1.z, wa[6], accA[kk]);
                    accA[kk] = fmaf(a1.w, wa[7], accA[kk]);
                    accB[kk] = fmaf(a0.x, wbv[0], accB[kk]);
                    accB[kk] = fmaf(a0.y, wbv[1], accB[kk]);
                    accB[kk] = fmaf(a0.z, wbv[2], accB[kk]);
                    accB[kk] = fmaf(a0.w, wbv[3], accB[kk]);
                    accB[kk] = fmaf(a1.x, wbv[4], accB[kk]);
                    accB[kk] = fmaf(a1.y, wbv[5], accB[kk]);
                    accB[kk] = fmaf(a1.z, wbv[6], accB[kk]);
                    accB[kk] = fmaf(a1.w, wbv[7], accB[kk]);
                }
            }
            // coord tail (W1 cols 0..2)
            float ta0=W1[o1*131+0], ta1=W1[o1*131+1], ta2=W1[o1*131+2];
            float tb0=W1[o2*131+0], tb1=W1[o2*131+1], tb2=W1[o2*131+2];
            float biasA = B1[o1], biasB = B1[o2];
#pragma unroll
            for (int kk = 0; kk < 8; ++kk) {
                int k = g*8 + kk;
                float f0 = inb_[k][128], f1 = inb_[k][129], f2 = inb_[k][130];
                float vA = accA[kk];
                vA = fmaf(f0, ta0, vA); vA = fmaf(f1, ta1, vA); vA = fmaf(f2, ta2, vA);
                float vB = accB[kk];
                vB = fmaf(f0, tb0, vB); vB = fmaf(f1, tb1, vB); vB = fmaf(f2, tb2, vB);
                h1_[k][o1] = fmaxf(vA + biasA, 0.f);
                h1_[k][o2] = fmaxf(vB + biasB, 0.f);
            }
        }
        __syncthreads();
        {   // L2: 128 -> 128, 2 outputs x 8 samples per thread
            float accA[8] = {}, accB[8] = {};
            for (int ch = 0; ch < 16; ++ch) {
                const float4 wa0 = *(const float4*)&W2[o1*128 + ch*8];
                const float4 wa1 = *(const float4*)&W2[o1*128 + ch*8 + 4];
                const float4 wb0 = *(const float4*)&W2[o2*128 + ch*8];
                const float4 wb1 = *(const float4*)&W2[o2*128 + ch*8 + 4];
#pragma unroll
                for (int kk = 0; kk < 8; ++kk) {
                    int k = g*8 + kk;
                    const float4 a0 = *(const float4*)&h1_[k][ch*8];
                    const float4 a1 = *(const float4*)&h1_[k][ch*8+4];
                    accA[kk] = fmaf(a0.x, wa0.x, accA[kk]);
                    accA[kk] = fmaf(a0.y, wa0.y, accA[kk]);
                    accA[kk] = fmaf(a0.z, wa0.z, accA[kk]);
                    accA[kk] = fmaf(a0.w, wa0.w, accA[kk]);
                    accA[kk] = fmaf(a1.x, wa1.x, accA[kk]);
                    accA[kk] = fmaf(a1.y, wa1.y, accA[kk]);
                    accA[kk] = fmaf(a1.z, wa1.z, accA[kk]);
                    accA[kk] = fmaf(a1.w, wa1.w, accA[kk]);
                    accB[kk] = fmaf(a0.x, wb0.x, accB[kk]);
                    accB[kk] = fmaf(a0.y, wb0.y, accB[kk]);
                    accB[kk] = fmaf(a0.z, wb0.z, accB[kk]);
                    accB[kk] = fmaf(a0.w, wb0.w, accB[kk]);
                    accB[kk] = fmaf(a1.x, wb1.x, accB[kk]);
                    accB[kk] = fmaf(a1.y, wb1.y, accB[kk]);
                    accB[kk] = fmaf(a1.z, wb1.z, accB[kk]);
                    accB[kk] = fmaf(a1.w, wb1.w, accB[kk]);
                }
            }
            float biasA = B2[o1], biasB = B2[o2];
#pragma unroll
            for (int kk = 0; kk < 8; ++kk) {
                int k = g*8 + kk;
                h2_[k][o1] = fmaxf(accA[kk] + biasA, 0.f);
                h2_[k][o2] = fmaxf(accB[kk] + biasB, 0.f);
            }
        }
        __syncthreads();
        {   // L3: 128 -> 285, fold max over this half's 32 samples
            {
                float acc[32] = {};
                for (int ch = 0; ch < 16; ++ch) {
                    const float4 w0 = *(const float4*)&W3[t*128 + ch*8];
                    const float4 w1 = *(const float4*)&W3[t*128 + ch*8 + 4];
#pragma unroll
                    for (int kk = 0; kk < 32; ++kk) {
                        const float4 a0 = *(const float4*)&h2_[kk][ch*8];
                        const float4 a1 = *(const float4*)&h2_[kk][ch*8+4];
                        acc[kk] = fmaf(a0.x, w0.x, acc[kk]);
                        acc[kk] = fmaf(a0.y, w0.y, acc[kk]);
                        acc[kk] = fmaf(a0.z, w0.z, acc[kk]);
                        acc[kk] = fmaf(a0.w, w0.w, acc[kk]);
                        acc[kk] = fmaf(a1.x, w1.x, acc[kk]);
                        acc[kk] = fmaf(a1.y, w1.y, acc[kk]);
                        acc[kk] = fmaf(a1.z, w1.z, acc[kk]);
                        acc[kk] = fmaf(a1.w, w1.w, acc[kk]);
                    }
                }
                float bias = B3[t];
                float mm = vmax0;
#pragma unroll
                for (int kk = 0; kk < 32; ++kk) mm = fmaxf(mm, fmaxf(acc[kk] + bias, 0.f));
                vmax0 = mm;
            }
            if (t < 29) {
                int o = t + 256;
                float acc[32] = {};
                for (int ch = 0; ch < 16; ++ch) {
                    const float4 w0 = *(const float4*)&W3[o*128 + ch*8];
                    const float4 w1 = *(const float4*)&W3[o*128 + ch*8 + 4];
#pragma unroll
                    for (int kk = 0; kk < 32; ++kk) {
                        const float4 a0 = *(const float4*)&h2_[kk][ch*8];
                        const float4 a1 = *(const float4*)&h2_[kk][ch*8+4];
                        acc[kk] = fmaf(a0.x, w0.x, acc[kk]);
                        acc[kk] = fmaf(a0.y, w0.y, acc[kk]);
                        acc[kk] = fmaf(a0.z, w0.z, acc[kk]);
                        acc[kk] = fmaf(a0.w, w0.w, acc[kk]);
                        acc[kk] = fmaf(a1.x, w1.x, acc[kk]);
                        acc[kk] = fmaf(a1.y, w1.y, acc[kk]);
                        acc[kk] = fmaf(a1.z, w1.z, acc[kk]);
                        acc[kk] = fmaf(a1.w, w1.w, acc[kk]);
                    }
                }
                float bias = B3[o];
                float mm = vmax1;
#pragma unroll
                for (int kk = 0; kk < 32; ++kk) mm = fmaxf(mm, fmaxf(acc[kk] + bias, 0.f));
                vmax1 = mm;
            }
        }
    }
    out1[((size_t)b*NP2+s)*285 + t] = vmax0;
    if (t < 29) out1[((size_t)b*NP2+s)*285 + t + 256] = vmax1;
}

extern "C" void kernel_launch(void* const* d_in, const int* in_sizes, int n_in,
                              void* d_out, int out_size, void* d_ws, size_t ws_size,
                              hipStream_t stream)
{
    (void)in_sizes; (void)n_in; (void)out_size; (void)ws_size;
    const float* xyz  = (const float*)d_in[0];
    const float* s1w1 = (const float*)d_in[1];  const float* s1b1 = (const float*)d_in[2];
    const float* s1w2 = (const float*)d_in[3];  const float* s1b2 = (const float*)d_in[4];
    const float* s1w3 = (const float*)d_in[5];  const float* s1b3 = (const float*)d_in[6];
    const float* s2w1 = (const float*)d_in[7];  const float* s2b1 = (const float*)d_in[8];
    const float* s2w2 = (const float*)d_in[9];  const float* s2b2 = (const float*)d_in[10];
    const float* s2w3 = (const float*)d_in[11]; const float* s2b3 = (const float*)d_in[12];

    float* ws        = (float*)d_ws;
    float* new_xyz1  = ws;                  // 8*512*3   = 12288 f
    float* new_xyz2  = ws + 12288;          // 8*256*3   = 6144 f
    float* l1_points = ws + 18432;          // 8*512*128 = 524288 f
    int*   idx1      = (int*)(ws + 542720); // 8*512*32  = 131072 i
    int*   idx2      = idx1 + 131072;       // 8*256*64  = 131072 i
    // fps1 exchange slots: 8 batches x 2 parities x 16 blocks u64 (2 KB)
    unsigned long long* bests = (unsigned long long*)(ws + 804864);

    float* out0 = (float*)d_out;            // (8,3,256)
    float* out1 = out0 + 8*3*256;           // (8,256,285)

    const float r2a = (float)(0.025*0.025);
    const float r2b = (float)(0.05*0.05);

    stage1_kernel    <<<dim3(ST1_X, 8),   dim3(256), 0, stream>>>(xyz, new_xyz1, bests,
                         idx1, r2a, new_xyz2, out0);
    mlp1_ball2_kernel<<<dim3(NP1+NP2, 8), dim3(256), 0, stream>>>(xyz, new_xyz1, idx1,
                         s1w1,s1b1,s1w2,s1b2,s1w3,s1b3, l1_points,
                         new_xyz2, idx2, r2b);
    mlp2_kernel      <<<dim3(NP2, 8),     dim3(256), 0, stream>>>(new_xyz1, l1_points,
                         new_xyz2, idx2, s2w1,s2b1,s2w2,s2b2,s2w3,s2b3, out1);
}

// Round 13
// 1699.561 us; speedup vs baseline: 1.2688x; 1.0542x over previous
//
#include <hip/hip_runtime.h>

#define N1 32768
#define NP1 512
#define NS1 32
#define N2 512
#define NP2 256
#define NS2 64
#define POISON 0xAAAAAAAAu

// ---- exact-rounding helpers: replicate reference op-by-op (NO fma/contract) ----
__device__ __forceinline__ float fadd(float a, float b){ return __fadd_rn(a,b); }
__device__ __forceinline__ float fmul(float a, float b){ return __fmul_rn(a,b); }
__device__ __forceinline__ float fsub(float a, float b){ return __fsub_rn(a,b); }

__device__ __forceinline__ float dist3(float px,float py,float pz,float cx,float cy,float cz){
    float dx = fsub(px,cx), dy = fsub(py,cy), dz = fsub(pz,cz);
    return fadd(fadd(fmul(dx,dx), fmul(dy,dy)), fmul(dz,dz));
}
__device__ __forceinline__ float sumsq3(float x,float y,float z){
    return fadd(fadd(fmul(x,x), fmul(y,y)), fmul(z,z));
}
__device__ __forceinline__ float dot3(float ax,float ay,float az,float bx,float by,float bz){
    return fadd(fadd(fmul(ax,bx), fmul(ay,by)), fmul(az,bz));
}
__device__ __forceinline__ unsigned long long shflmax64(unsigned long long k, int off){
    unsigned long long o = __shfl_xor(k, off, 64);
    return o > k ? o : k;
}

// ---- agent-scope atomic publish / poison-poll consume ----
// s_sleep operand must be a compile-time constant -> template parameter (R12 fix)
__device__ __forceinline__ void astore_f(float* p, float v){
    __hip_atomic_store((unsigned*)p, __float_as_uint(v), __ATOMIC_RELAXED, __HIP_MEMORY_SCOPE_AGENT);
}
__device__ __forceinline__ void astore_i(int* p, int v){
    __hip_atomic_store((unsigned*)p, (unsigned)v, __ATOMIC_RELAXED, __HIP_MEMORY_SCOPE_AGENT);
}
template<int SLP>
__device__ __forceinline__ float poll_f(const float* p){
    unsigned v;
    for(;;){
        v = __hip_atomic_load((const unsigned*)p, __ATOMIC_RELAXED, __HIP_MEMORY_SCOPE_AGENT);
        if (v != POISON) break;
        __builtin_amdgcn_s_sleep(SLP);
    }
    return __uint_as_float(v);
}
template<int SLP>
__device__ __forceinline__ int poll_i(const int* p){
    unsigned v;
    for(;;){
        v = __hip_atomic_load((const unsigned*)p, __ATOMIC_RELAXED, __HIP_MEMORY_SCOPE_AGENT);
        if (v != POISON) break;
        __builtin_amdgcn_s_sleep(SLP);
    }
    return (int)v;
}

// ==================  ONE MEGA KERNEL: all six stages, poll-chained  ==================
// 1-D grid, stage-major dispatch order (producers strictly before consumers):
//   [0,128)      fps1   (m = l%16, b = l/16  — R6 adjacency, proven stable)
//   [128,1152)   ball1  (4 centroids/block, poll new_xyz1[s])
//   [1152,1160)  fps2   (poll all new_xyz1)
//   [1160,5256)  mlp1   (1 centroid/block, poll idx1[s])
//   [5256,5768)  ball2  (4 centroids/block, poll new_xyz2[s])
//   [5768,7816)  mlp2   (1 centroid/block, poll idx2[s] + l1_points)
// All cross-stage traffic: relaxed agent atomics (publish) + poison-poll
// (consume). 0xAA poison is unreachable for every published value (coords in
// [0,1), post-ReLU feats >= 0, indices in [0,32768)). Each stage polls only
// earlier-dispatched stages -> grounded, no deadlock; ws re-poisoned per
// launch -> graph-replay-safe.
#define FPS1_M  16
#define L_B1   128
#define L_F2   1152
#define L_M1   1160
#define L_B2   5256
#define L_M2   5768
#define L_TOT  7816

__global__ __launch_bounds__(256) void mega_kernel(const float* __restrict__ xyz,
    float* __restrict__ new_xyz1, unsigned long long* __restrict__ bests,
    int* __restrict__ idx1, float r2a,
    float* __restrict__ new_xyz2, float* __restrict__ out0,
    const float* __restrict__ M1W1, const float* __restrict__ M1B1,
    const float* __restrict__ M1W2, const float* __restrict__ M1B2,
    const float* __restrict__ M1W3, const float* __restrict__ M1B3,
    float* __restrict__ l1_points,
    int* __restrict__ idx2, float r2b,
    const float* __restrict__ M2W1, const float* __restrict__ M2B1,
    const float* __restrict__ M2W2, const float* __restrict__ M2B2,
    const float* __restrict__ M2W3, const float* __restrict__ M2B3,
    float* __restrict__ out1)
{
    const int l = blockIdx.x;
    const int t = threadIdx.x;
    const int lane = t & 63;
    const int wid  = t >> 6;

    __shared__ unsigned long long wb[4];
    __shared__ float cw[4];
    __shared__ __align__(16) float ldsA[32*132];   // 16896 B (multi-purpose)
    __shared__ __align__(16) float ldsB[32*128];   // 16384 B
    __shared__ int sidx_sh[64];

    if (l < L_B1) {
        // ---------------- fps1 (R6-exact body; proven 1016us stable) ----------------
        const int m = l & 15;
        const int b = l >> 4;
        const float* xb = xyz + (size_t)b * 6 * N1;
        const int base = m * (N1 / FPS1_M);
        float px[8], py[8], pz[8], dd[8];
#pragma unroll
        for (int j = 0; j < 8; ++j) {
            int n = base + t + j * 256;
            px[j] = xb[n];
            py[j] = xb[N1 + n];
            pz[j] = xb[2*N1 + n];
            dd[j] = 1e10f;
        }
        float cx = xb[0], cy = xb[N1], cz = xb[2*N1];

        for (int s = 0; s < NP1; ++s) {
            if (m == 0 && t == 0) {
                float* o = new_xyz1 + ((size_t)b*NP1 + s)*3;
                astore_f(o+0, cx); astore_f(o+1, cy); astore_f(o+2, cz);
            }
            if (s == NP1 - 1) break;

            float bv = -1.0f; int bi = base + t;
#pragma unroll
            for (int j = 0; j < 8; ++j) {
                float d  = dist3(px[j],py[j],pz[j],cx,cy,cz);
                float nd = fminf(dd[j], d);
                dd[j] = nd;
                if (nd > bv) { bv = nd; bi = base + t + j*256; }
            }
            unsigned long long pk = ((unsigned long long)__float_as_uint(bv) << 15)
                                  | (unsigned long long)(32767 - bi);
            pk = shflmax64(pk, 1);  pk = shflmax64(pk, 2);  pk = shflmax64(pk, 4);
            pk = shflmax64(pk, 8);  pk = shflmax64(pk, 16); pk = shflmax64(pk, 32);
            if (lane == 0) wb[wid] = pk;
            __syncthreads();

            if (wid == 0) {
                unsigned long long k4 = (lane < 4) ? wb[lane] : 0ull;
                k4 = shflmax64(k4, 1); k4 = shflmax64(k4, 2);
                unsigned long long* slotPar = bests + ((size_t)b*2 + (s & 1))*FPS1_M;
                if (lane == 0)
                    __hip_atomic_store(slotPar + m, (k4 << 10) | (unsigned long long)s,
                                       __ATOMIC_RELAXED, __HIP_MEMORY_SCOPE_AGENT);
                unsigned long long myv = 0; bool done = (lane >= FPS1_M);
                float ccx = 0.f, ccy = 0.f, ccz = 0.f;
                while (__ballot(done) != 0xFFFFFFFFFFFFFFFFull) {
                    if (!done) {
                        unsigned long long v = __hip_atomic_load(slotPar + lane,
                                                 __ATOMIC_RELAXED, __HIP_MEMORY_SCOPE_AGENT);
                        if ((unsigned)(v & 1023ull) == (unsigned)s) {
                            done = true; myv = v;
                            int idx = 32767 - (int)((v >> 10) & 0x7fffull);
                            ccx = xb[idx]; ccy = xb[N1 + idx]; ccz = xb[2*N1 + idx];
                        }
                    }
                }
                unsigned long long w = myv;
                w = shflmax64(w, 1); w = shflmax64(w, 2); w = shflmax64(w, 4); w = shflmax64(w, 8);
                int wl = (int)__ffsll(__ballot(myv == w)) - 1;
                float ncx = __shfl(ccx, wl, 64);
                float ncy = __shfl(ccy, wl, 64);
                float ncz = __shfl(ccz, wl, 64);
                if (lane == 0) { cw[0] = ncx; cw[1] = ncy; cw[2] = ncz; }
            }
            __syncthreads();
            cx = cw[0]; cy = cw[1]; cz = cw[2];
        }
        return;
    }

    if (l < L_F2) {
        // ---------------- ball1: 4 centroids/block, 1/wave ----------------
        const int i = l - L_B1;
        const int b = i >> 7;
        const int s = (i & 127)*4 + wid;
        const float* xb = xyz + (size_t)b*6*N1;
        const float* cp = new_xyz1 + ((size_t)b*NP1 + s)*3;
        float cx = poll_f<32>(cp+0), cy = poll_f<32>(cp+1), cz = poll_f<32>(cp+2);

        float snew = sumsq3(cx,cy,cz);
        int* out = idx1 + ((size_t)b*NP1 + s)*NS1;
        int cnt = 0, first = 0;
        for (int ch = 0; ch < N1/64; ++ch) {
            int n = ch*64 + lane;
            float x = xb[n], y = xb[N1+n], z = xb[2*N1+n];
            float sx  = sumsq3(x,y,z);
            float dt  = dot3(cx,cy,cz,x,y,z);
            float sqr = fsub(fadd(snew, sx), fmul(2.0f, dt));
            bool inb = !(sqr > r2a);
            unsigned long long mask = __ballot(inb);
            if (mask) {
                if (cnt == 0) first = ch*64 + (int)(__ffsll((unsigned long long)mask) - 1);
                if (inb) {
                    int pos = cnt + (int)__popcll(mask & ((1ull << lane) - 1ull));
                    if (pos < NS1) astore_i(out + pos, n);
                }
                cnt += (int)__popcll(mask);
                if (cnt >= NS1) break;
            }
        }
        int c = cnt < NS1 ? cnt : NS1;
        if (lane < NS1 && lane >= c) astore_i(out + lane, first);
        return;
    }

    if (l < L_M1) {
        // ---------------- fps2: poll-stage new_xyz1, 1-wave FPS ----------------
        const int b = l - L_F2;
        float* c3 = ldsA;
        const float* src = new_xyz1 + (size_t)b*N2*3;
        for (int e = t; e < N2*3; e += 256) c3[e] = poll_f<32>(src + e);
        __syncthreads();
        if (t >= 64) return;

        float px[8], py[8], pz[8], dd[8];
#pragma unroll
        for (int j = 0; j < 8; ++j) {
            int n = t + j*64;
            px[j] = c3[n*3]; py[j] = c3[n*3+1]; pz[j] = c3[n*3+2];
            dd[j] = 1e10f;
        }
        int cur = 0;
        for (int s = 0; s < NP2; ++s) {
            float cx = c3[cur*3], cy = c3[cur*3+1], cz = c3[cur*3+2];
            if (t == 0) {
                float* o = new_xyz2 + ((size_t)b*NP2 + s)*3;
                astore_f(o+0, cx); astore_f(o+1, cy); astore_f(o+2, cz);
                out0[b*3*NP2 + s]         = cx;
                out0[b*3*NP2 + NP2 + s]   = cy;
                out0[b*3*NP2 + 2*NP2 + s] = cz;
            }
            float bv = -1.0f; int bi = 0;
#pragma unroll
            for (int j = 0; j < 8; ++j) {
                float d  = dist3(px[j],py[j],pz[j],cx,cy,cz);
                float nd = fminf(dd[j], d);
                dd[j] = nd;
                int n = t + j*64;
                if (nd > bv) { bv = nd; bi = n; }
            }
            unsigned long long pk = ((unsigned long long)__float_as_uint(bv) << 9)
                                  | (unsigned long long)(511 - bi);
            pk = shflmax64(pk, 1);  pk = shflmax64(pk, 2);  pk = shflmax64(pk, 4);
            pk = shflmax64(pk, 8);  pk = shflmax64(pk, 16); pk = shflmax64(pk, 32);
            cur = 511 - (int)(pk & 511ull);
        }
        return;
    }

    if (l < L_B2) {
        // ---------------- mlp1: 1 centroid/block (R6 body + polls) ----------------
        const int i = l - L_M1;
        const int b = i >> 9;
        const int s = i & 511;
        const float* xb = xyz + (size_t)b*6*N1;
        float (*inb6)[6]   = (float(*)[6])ldsA;            // 192 f
        float (*h1m)[64]   = (float(*)[64])(ldsA + 192);   // 2048 f
        float (*h2m)[64]   = (float(*)[64])ldsB;           // 2048 f
        float (*redm)[128] = (float(*)[128])(ldsB + 2048); // 256 f

        const float* cp = new_xyz1 + ((size_t)b*NP1 + s)*3;
        float c0 = poll_f<32>(cp+0), c1 = poll_f<32>(cp+1), c2 = poll_f<32>(cp+2);
        if (t < NS1) sidx_sh[t] = poll_i<32>(idx1 + ((size_t)b*NP1+s)*NS1 + t);
        __syncthreads();
        if (t < NS1*6) {
            int k = t / 6, c = t % 6;
            int n = sidx_sh[k];
            float v = xb[(size_t)c*N1 + n];
            if (c == 0) v -= c0; else if (c == 1) v -= c1; else if (c == 2) v -= c2;
            inb6[k][c] = v;
        }
        __syncthreads();
        {   // L1
            int o = t & 63, kg = t >> 6;
            float w[6];
#pragma unroll
            for (int c = 0; c < 6; ++c) w[c] = M1W1[o*6+c];
            float bias = M1B1[o];
#pragma unroll
            for (int kk = 0; kk < 8; ++kk) {
                int k = kg*8 + kk;
                float a = 0.f;
#pragma unroll
                for (int c = 0; c < 6; ++c) a = fmaf(inb6[k][c], w[c], a);
                h1m[k][o] = fmaxf(a + bias, 0.f);
            }
        }
        __syncthreads();
        {   // L2: 64 -> 64
            int o = t & 63, kg = t >> 6;
            float acc[8] = {};
            for (int ch = 0; ch < 8; ++ch) {
                const float4 wa = *(const float4*)&M1W2[o*64 + ch*8];
                const float4 wbv = *(const float4*)&M1W2[o*64 + ch*8 + 4];
#pragma unroll
                for (int kk = 0; kk < 8; ++kk) {
                    int k = kg*8+kk;
                    const float4 a0 = *(const float4*)&h1m[k][ch*8];
                    const float4 a1 = *(const float4*)&h1m[k][ch*8+4];
                    acc[kk] = fmaf(a0.x, wa.x, acc[kk]);
                    acc[kk] = fmaf(a0.y, wa.y, acc[kk]);
                    acc[kk] = fmaf(a0.z, wa.z, acc[kk]);
                    acc[kk] = fmaf(a0.w, wa.w, acc[kk]);
                    acc[kk] = fmaf(a1.x, wbv.x, acc[kk]);
                    acc[kk] = fmaf(a1.y, wbv.y, acc[kk]);
                    acc[kk] = fmaf(a1.z, wbv.z, acc[kk]);
                    acc[kk] = fmaf(a1.w, wbv.w, acc[kk]);
                }
            }
            float bias = M1B2[o];
#pragma unroll
            for (int kk = 0; kk < 8; ++kk) h2m[kg*8+kk][o] = fmaxf(acc[kk] + bias, 0.f);
        }
        __syncthreads();
        {   // L3: 64 -> 128 + max over samples
            int o = t & 127, kg = t >> 7;
            float acc[16] = {};
            for (int ch = 0; ch < 8; ++ch) {
                const float4 wa = *(const float4*)&M1W3[o*64 + ch*8];
                const float4 wbv = *(const float4*)&M1W3[o*64 + ch*8 + 4];
#pragma unroll
                for (int kk = 0; kk < 16; ++kk) {
                    int k = kg*16+kk;
                    const float4 a0 = *(const float4*)&h2m[k][ch*8];
                    const float4 a1 = *(const float4*)&h2m[k][ch*8+4];
                    acc[kk] = fmaf(a0.x, wa.x, acc[kk]);
                    acc[kk] = fmaf(a0.y, wa.y, acc[kk]);
                    acc[kk] = fmaf(a0.z, wa.z, acc[kk]);
                    acc[kk] = fmaf(a0.w, wa.w, acc[kk]);
                    acc[kk] = fmaf(a1.x, wbv.x, acc[kk]);
                    acc[kk] = fmaf(a1.y, wbv.y, acc[kk]);
                    acc[kk] = fmaf(a1.z, wbv.z, acc[kk]);
                    acc[kk] = fmaf(a1.w, wbv.w, acc[kk]);
                }
            }
            float bias = M1B3[o];
            float m = -1e30f;
#pragma unroll
            for (int kk = 0; kk < 16; ++kk) m = fmaxf(m, fmaxf(acc[kk] + bias, 0.f));
            redm[kg][o] = m;
        }
        __syncthreads();
        if (t < 128) {
            float m = fmaxf(redm[0][t], redm[1][t]);
            astore_f(l1_points + ((size_t)b*NP1+s)*128 + t, m);
        }
        return;
    }

    if (l < L_M2) {
        // ---------------- ball2: 4 centroids/block, 1/wave ----------------
        const int i = l - L_B2;
        const int b = i >> 6;
        const int s = (i & 63)*4 + wid;
        const float* pb = new_xyz1 + (size_t)b*N2*3;
        const float* cp = new_xyz2 + ((size_t)b*NP2 + s)*3;
        float cx = poll_f<32>(cp+0), cy = poll_f<32>(cp+1), cz = poll_f<32>(cp+2);
        float snew = sumsq3(cx,cy,cz);
        int* out = idx2 + ((size_t)b*NP2 + s)*NS2;
        int cnt = 0, first = 0;
        for (int ch = 0; ch < N2/64; ++ch) {
            int n = ch*64 + lane;
            float x = poll_f<8>(&pb[n*3]), y = poll_f<8>(&pb[n*3+1]), z = poll_f<8>(&pb[n*3+2]);
            float sx  = sumsq3(x,y,z);
            float dt  = dot3(cx,cy,cz,x,y,z);
            float sqr = fsub(fadd(snew, sx), fmul(2.0f, dt));
            bool inb = !(sqr > r2b);
            unsigned long long mask = __ballot(inb);
            if (mask) {
                if (cnt == 0) first = ch*64 + (int)(__ffsll((unsigned long long)mask) - 1);
                if (inb) {
                    int pos = cnt + (int)__popcll(mask & ((1ull << lane) - 1ull));
                    if (pos < NS2) astore_i(out + pos, n);
                }
                cnt += (int)__popcll(mask);
                if (cnt >= NS2) break;
            }
        }
        int c = cnt < NS2 ? cnt : NS2;
        if (lane >= c) astore_i(out + lane, first);
        return;
    }

    // ---------------- mlp2: 1 centroid/block (R6 body + polls, LDS-aliased) ----------------
    {
        const int i = l - L_M2;
        const int b = i >> 8;
        const int s = i & 255;
        float (*inb2)[132] = (float(*)[132])ldsA;   // aliased with h2_ (inb dead after L1)
        float (*h1_)[128]  = (float(*)[128])ldsB;
        float (*h2_)[128]  = (float(*)[128])ldsA;

        const float* cp = new_xyz2 + ((size_t)b*NP2+s)*3;
        float c0 = poll_f<32>(cp+0), c1 = poll_f<32>(cp+1), c2 = poll_f<32>(cp+2);
        if (t < NS2) sidx_sh[t] = poll_i<32>(idx2 + ((size_t)b*NP2+s)*NS2 + t);

        const int o1 = t & 63, o2 = o1 + 64, g = t >> 6;
        float vmax0 = -1e30f, vmax1 = -1e30f;

        for (int half = 0; half < 2; ++half) {
            __syncthreads();
            // stage features (per-dword poison-poll atomic loads) + rel coords
            for (int e = t; e < 32*128; e += 256) {
                int kk = e >> 7, c = e & 127;
                int n = sidx_sh[half*32 + kk];
                inb2[kk][c] = poll_f<8>(l1_points + ((size_t)b*N2 + n)*128 + c);
            }
            for (int e = t; e < 32*3; e += 256) {
                int kk = e / 3, c = e % 3;
                int n = sidx_sh[half*32 + kk];
                inb2[kk][128 + c] = poll_f<8>(new_xyz1 + ((size_t)b*N2 + n)*3 + c)
                                  - (c==0 ? c0 : (c==1 ? c1 : c2));
            }
            __syncthreads();
            {   // L1: 131 -> 128, 2 outputs x 8 samples per thread
                float accA[8] = {}, accB[8] = {};
                for (int ch = 0; ch < 16; ++ch) {
                    float wa[8], wbv[8];
#pragma unroll
                    for (int j = 0; j < 8; ++j) {
                        wa[j]  = M2W1[o1*131 + 3 + ch*8 + j];
                        wbv[j] = M2W1[o2*131 + 3 + ch*8 + j];
                    }
#pragma unroll
                    for (int kk = 0; kk < 8; ++kk) {
                        int k = g*8 + kk;
                        const float4 a0 = *(const float4*)&inb2[k][ch*8];
                        const float4 a1 = *(const float4*)&inb2[k][ch*8+4];
                        accA[kk] = fmaf(a0.x, wa[0], accA[kk]);
                        accA[kk] = fmaf(a0.y, wa[1], accA[kk]);
                        accA[kk] = fmaf(a0.z, wa[2], accA[kk]);
                        accA[kk] = fmaf(a0.w, wa[3], accA[kk]);
                        accA[kk] = fmaf(a1.x, wa[4], accA[kk]);
                        accA[kk] = fmaf(a1.y, wa[5], accA[kk]);
                        accA[kk] = fmaf(a1.z, wa[6], accA[kk]);
                        accA[kk] = fmaf(a1.w, wa[7], accA[kk]);
                        accB[kk] = fmaf(a0.x, wbv[0], accB[kk]);
                        accB[kk] = fmaf(a0.y, wbv[1], accB[kk]);
                        accB[kk] = fmaf(a0.z, wbv[2], accB[kk]);
                        accB[kk] = fmaf(a0.w, wbv[3], accB[kk]);
                        accB[kk] = fmaf(a1.x, wbv[4], accB[kk]);
                        accB[kk] = fmaf(a1.y, wbv[5], accB[kk]);
                        accB[kk] = fmaf(a1.z, wbv[6], accB[kk]);
                        accB[kk] = fmaf(a1.w, wbv[7], accB[kk]);
                    }
                }
                float ta0=M2W1[o1*131+0], ta1=M2W1[o1*131+1], ta2=M2W1[o1*131+2];
                float tb0=M2W1[o2*131+0], tb1=M2W1[o2*131+1], tb2=M2W1[o2*131+2];
                float biasA = M2B1[o1], biasB = M2B1[o2];
#pragma unroll
                for (int kk = 0; kk < 8; ++kk) {
                    int k = g*8 + kk;
                    float f0 = inb2[k][128], f1 = inb2[k][129], f2 = inb2[k][130];
                    float vA = accA[kk];
                    vA = fmaf(f0, ta0, vA); vA = fmaf(f1, ta1, vA); vA = fmaf(f2, ta2, vA);
                    float vB = accB[kk];
                    vB = fmaf(f0, tb0, vB); vB = fmaf(f1, tb1, vB); vB = fmaf(f2, tb2, vB);
                    h1_[k][o1] = fmaxf(vA + biasA, 0.f);
                    h1_[k][o2] = fmaxf(vB + biasB, 0.f);
                }
            }
            __syncthreads();
            {   // L2: 128 -> 128 (writes h2_ = alias of inb2; inb2 is dead now)
                float accA[8] = {}, accB[8] = {};
                for (int ch = 0; ch < 16; ++ch) {
                    const float4 wa0 = *(const float4*)&M2W2[o1*128 + ch*8];
                    const float4 wa1 = *(const float4*)&M2W2[o1*128 + ch*8 + 4];
                    const float4 wb0 = *(const float4*)&M2W2[o2*128 + ch*8];
                    const float4 wb1 = *(const float4*)&M2W2[o2*128 + ch*8 + 4];
#pragma unroll
                    for (int kk = 0; kk < 8; ++kk) {
                        int k = g*8 + kk;
                        const float4 a0 = *(const float4*)&h1_[k][ch*8];
                        const float4 a1 = *(const float4*)&h1_[k][ch*8+4];
                        accA[kk] = fmaf(a0.x, wa0.x, accA[kk]);
                        accA[kk] = fmaf(a0.y, wa0.y, accA[kk]);
                        accA[kk] = fmaf(a0.z, wa0.z, accA[kk]);
                        accA[kk] = fmaf(a0.w, wa0.w, accA[kk]);
                        accA[kk] = fmaf(a1.x, wa1.x, accA[kk]);
                        accA[kk] = fmaf(a1.y, wa1.y, accA[kk]);
                        accA[kk] = fmaf(a1.z, wa1.z, accA[kk]);
                        accA[kk] = fmaf(a1.w, wa1.w, accA[kk]);
                        accB[kk] = fmaf(a0.x, wb0.x, accB[kk]);
                        accB[kk] = fmaf(a0.y, wb0.y, accB[kk]);
                        accB[kk] = fmaf(a0.z, wb0.z, accB[kk]);
                        accB[kk] = fmaf(a0.w, wb0.w, accB[kk]);
                        accB[kk] = fmaf(a1.x, wb1.x, accB[kk]);
                        accB[kk] = fmaf(a1.y, wb1.y, accB[kk]);
                        accB[kk] = fmaf(a1.z, wb1.z, accB[kk]);
                        accB[kk] = fmaf(a1.w, wb1.w, accB[kk]);
                    }
                }
                float biasA = M2B2[o1], biasB = M2B2[o2];
#pragma unroll
                for (int kk = 0; kk < 8; ++kk) {
                    int k = g*8 + kk;
                    h2_[k][o1] = fmaxf(accA[kk] + biasA, 0.f);
                    h2_[k][o2] = fmaxf(accB[kk] + biasB, 0.f);
                }
            }
            __syncthreads();
            {   // L3: 128 -> 285, fold max over this half's 32 samples
                {
                    float acc[32] = {};
                    for (int ch = 0; ch < 16; ++ch) {
                        const float4 w0 = *(const float4*)&M2W3[t*128 + ch*8];
                        const float4 w1 = *(const float4*)&M2W3[t*128 + ch*8 + 4];
#pragma unroll
                        for (int kk = 0; kk < 32; ++kk) {
                            const float4 a0 = *(const float4*)&h2_[kk][ch*8];
                            const float4 a1 = *(const float4*)&h2_[kk][ch*8+4];
                            acc[kk] = fmaf(a0.x, w0.x, acc[kk]);
                            acc[kk] = fmaf(a0.y, w0.y, acc[kk]);
                            acc[kk] = fmaf(a0.z, w0.z, acc[kk]);
                            acc[kk] = fmaf(a0.w, w0.w, acc[kk]);
                            acc[kk] = fmaf(a1.x, w1.x, acc[kk]);
                            acc[kk] = fmaf(a1.y, w1.y, acc[kk]);
                            acc[kk] = fmaf(a1.z, w1.z, acc[kk]);
                            acc[kk] = fmaf(a1.w, w1.w, acc[kk]);
                        }
                    }
                    float bias = M2B3[t];
                    float mm = vmax0;
#pragma unroll
                    for (int kk = 0; kk < 32; ++kk) mm = fmaxf(mm, fmaxf(acc[kk] + bias, 0.f));
                    vmax0 = mm;
                }
                if (t < 29) {
                    int o = t + 256;
                    float acc[32] = {};
                    for (int ch = 0; ch < 16; ++ch) {
                        const float4 w0 = *(const float4*)&M2W3[o*128 + ch*8];
                        const float4 w1 = *(const float4*)&M2W3[o*128 + ch*8 + 4];
#pragma unroll
                        for (int kk = 0; kk < 32; ++kk) {
                            const float4 a0 = *(const float4*)&h2_[kk][ch*8];
                            const float4 a1 = *(const float4*)&h2_[kk][ch*8+4];
                            acc[kk] = fmaf(a0.x, w0.x, acc[kk]);
                            acc[kk] = fmaf(a0.y, w0.y, acc[kk]);
                            acc[kk] = fmaf(a0.z, w0.z, acc[kk]);
                            acc[kk] = fmaf(a0.w, w0.w, acc[kk]);
                            acc[kk] = fmaf(a1.x, w1.x, acc[kk]);
                            acc[kk] = fmaf(a1.y, w1.y, acc[kk]);
                            acc[kk] = fmaf(a1.z, w1.z, acc[kk]);
                            acc[kk] = fmaf(a1.w, w1.w, acc[kk]);
                        }
                    }
                    float bias = M2B3[o];
                    float mm = vmax1;
#pragma unroll
                    for (int kk = 0; kk < 32; ++kk) mm = fmaxf(mm, fmaxf(acc[kk] + bias, 0.f));
                    vmax1 = mm;
                }
            }
        }
        out1[((size_t)b*NP2+s)*285 + t] = vmax0;
        if (t < 29) out1[((size_t)b*NP2+s)*285 + t + 256] = vmax1;
    }
}

extern "C" void kernel_launch(void* const* d_in, const int* in_sizes, int n_in,
                              void* d_out, int out_size, void* d_ws, size_t ws_size,
                              hipStream_t stream)
{
    (void)in_sizes; (void)n_in; (void)out_size; (void)ws_size;
    const float* xyz  = (const float*)d_in[0];
    const float* s1w1 = (const float*)d_in[1];  const float* s1b1 = (const float*)d_in[2];
    const float* s1w2 = (const float*)d_in[3];  const float* s1b2 = (const float*)d_in[4];
    const float* s1w3 = (const float*)d_in[5];  const float* s1b3 = (const float*)d_in[6];
    const float* s2w1 = (const float*)d_in[7];  const float* s2b1 = (const float*)d_in[8];
    const float* s2w2 = (const float*)d_in[9];  const float* s2b2 = (const float*)d_in[10];
    const float* s2w3 = (const float*)d_in[11]; const float* s2b3 = (const float*)d_in[12];

    float* ws        = (float*)d_ws;
    float* new_xyz1  = ws;                  // 8*512*3   = 12288 f
    float* new_xyz2  = ws + 12288;          // 8*256*3   = 6144 f
    float* l1_points = ws + 18432;          // 8*512*128 = 524288 f
    int*   idx1      = (int*)(ws + 542720); // 8*512*32  = 131072 i
    int*   idx2      = idx1 + 131072;       // 8*256*64  = 131072 i
    unsigned long long* bests = (unsigned long long*)(ws + 804864); // 256 u64

    float* out0 = (float*)d_out;            // (8,3,256)
    float* out1 = out0 + 8*3*256;           // (8,256,285)

    const float r2a = (float)(0.025*0.025);
    const float r2b = (float)(0.05*0.05);

    mega_kernel<<<dim3(L_TOT), dim3(256), 0, stream>>>(xyz,
        new_xyz1, bests, idx1, r2a, new_xyz2, out0,
        s1w1,s1b1,s1w2,s1b2,s1w3,s1b3, l1_points,
        idx2, r2b,
        s2w1,s2b1,s2w2,s2b2,s2w3,s2b3, out1);
}